// Round 5
// baseline (253.428 us; speedup 1.0000x reference)
//
#include <hip/hip_runtime.h>
#include <math.h>

static constexpr int B_  = 2;
static constexpr int S_  = 2048;
static constexpr int H_  = 16;
static constexpr int DH_ = 64;
// Q pre-scale = 1/sqrt(192) * log2(e) so flash softmax uses raw v_exp_f32 (exp2)
static constexpr float QSCALE2_ = 0.104117589f;
static constexpr float C8L2_    = 11.5415603f;     // 8 * log2(e) (static-max shift)

typedef __attribute__((ext_vector_type(8))) short short8;   // 8 x bf16
typedef __attribute__((ext_vector_type(4))) float floatx4;  // MFMA acc

__device__ __forceinline__ float bf2f(unsigned short u) {
    union { unsigned int i; float f; } c; c.i = ((unsigned int)u) << 16; return c.f;
}
__device__ __forceinline__ unsigned short f2bf(float f) {
    union { float f; unsigned int i; } c; c.f = f;
    unsigned int x = c.i;
    unsigned int r = (x + 0x7fffu + ((x >> 16) & 1u)) >> 16;
    if ((x & 0x7f800000u) == 0x7f800000u) r = x >> 16;   // inf/nan passthrough
    return (unsigned short)r;
}
__device__ __forceinline__ void load_lds16(const unsigned short* g, unsigned short* l) {
    __builtin_amdgcn_global_load_lds(
        (const __attribute__((address_space(1))) unsigned int*)g,
        (__attribute__((address_space(3))) unsigned int*)l, 16, 0, 0);
}

// ---------------------------------------------------------------------------
// prep: one launch doing cvt_x (blocks 0..4095), w_qkv transpose
// (4096..7167), w_out transpose (7168..8191).
// ---------------------------------------------------------------------------
__global__ __launch_bounds__(256) void prep(
    const float* __restrict__ x,     unsigned short* __restrict__ xb,
    const float* __restrict__ w_qkv, unsigned short* __restrict__ wqkvT,
    const float* __restrict__ w_out, unsigned short* __restrict__ woutT)
{
    __shared__ float t[32][33];
    const int bid = blockIdx.x;
    if (bid < 4096) {
        const int i = bid * 256 + threadIdx.x;
        const float4 v = reinterpret_cast<const float4*>(x)[i];
        ushort4 r;
        r.x = f2bf(v.x); r.y = f2bf(v.y); r.z = f2bf(v.z); r.w = f2bf(v.w);
        reinterpret_cast<ushort4*>(xb)[i] = r;
        return;
    }
    const float* in; unsigned short* out; int NN, bx, by;
    if (bid < 7168) {
        in = w_qkv; out = wqkvT; NN = 3072;
        const int b2 = bid - 4096; bx = b2 % 96; by = b2 / 96;
    } else {
        in = w_out; out = woutT; NN = 1024;
        const int b2 = bid - 7168; bx = b2 & 31; by = b2 >> 5;
    }
    const int n0 = bx * 32;
    const int k0 = by * 32;
    const int tn = threadIdx.x & 31, tk = threadIdx.x >> 5;   // tk 0..7
    #pragma unroll
    for (int i = 0; i < 4; ++i)
        t[tk + 8 * i][tn] = in[(size_t)(k0 + tk + 8 * i) * NN + n0 + tn];
    __syncthreads();
    #pragma unroll
    for (int i = 0; i < 4; ++i)
        out[(size_t)(n0 + tk + 8 * i) * 1024 + k0 + tn] = f2bf(t[tn][tk + 8 * i]);
}

// ---------------------------------------------------------------------------
// MFMA GEMM: C(128x128) = A(Mx1024 bf16) * BT(3072x1024 bf16)^T.
// bias + RoPE epilogue:
//   Q -> bf16 (B,H,S,DH), scaled by 1/sqrt(192)*log2e
//   K -> bf16 (B,H,S,DH)
//   V -> bf16 (B,H,DH,S)  TRANSPOSED (so flash reads V^T fragments directly)
// ---------------------------------------------------------------------------
__global__ __launch_bounds__(256) void gemm_qkv(
    const unsigned short* __restrict__ A, const unsigned short* __restrict__ BT,
    const float* __restrict__ bias,
    unsigned short* __restrict__ O0, unsigned short* __restrict__ O1,
    unsigned short* __restrict__ O2)
{
    __shared__ unsigned short As[128 * 32];
    __shared__ unsigned short Bs[128 * 32];

    const int tid  = threadIdx.x;
    const int wave = tid >> 6;
    const int lane = tid & 63;
    const int quad = lane >> 4;
    const int lm   = lane & 15;
    const int wm = (wave >> 1) * 64;
    const int wn = (wave & 1) * 64;
    const int n0 = blockIdx.x * 128;
    const int m0 = blockIdx.y * 128;

    floatx4 acc[4][4] = {};

    const int sr = lane >> 2;
    const int sc = lane & 3;

    for (int k0 = 0; k0 < 1024; k0 += 32) {
        #pragma unroll
        for (int rep = 0; rep < 2; ++rep) {
            const int r = wave * 32 + rep * 16;
            load_lds16(A  + (size_t)(m0 + r + sr) * 1024 + k0 + sc * 8, &As[r * 32]);
            load_lds16(BT + (size_t)(n0 + r + sr) * 1024 + k0 + sc * 8, &Bs[r * 32]);
        }
        __syncthreads();
        short8 af[4], bf[4];
        #pragma unroll
        for (int i = 0; i < 4; ++i) {
            af[i] = *reinterpret_cast<const short8*>(&As[(wm + i * 16 + lm) * 32 + quad * 8]);
            bf[i] = *reinterpret_cast<const short8*>(&Bs[(wn + i * 16 + lm) * 32 + quad * 8]);
        }
        #pragma unroll
        for (int mi = 0; mi < 4; ++mi)
            #pragma unroll
            for (int ni = 0; ni < 4; ++ni)
                acc[mi][ni] = __builtin_amdgcn_mfma_f32_16x16x32_bf16(
                    af[mi], bf[ni], acc[mi][ni], 0, 0, 0);
        __syncthreads();
    }

    const int nbase = n0 + wn;
    const int h   = nbase / 192;
    const int sec = (nbase - h * 192) >> 6;      // 0=q 1=k 2=v
    float bia[4];
    #pragma unroll
    for (int ni = 0; ni < 4; ++ni) bia[ni] = bias[nbase + ni * 16 + lm];
    unsigned short* Out = (sec == 0) ? O0 : ((sec == 1) ? O1 : O2);

    if (sec == 2) {
        // V^T store: (B,H,DH,S); lane holds 4 consecutive s -> ushort4
        #pragma unroll
        for (int mi = 0; mi < 4; ++mi) {
            const int m  = m0 + wm + mi * 16 + quad * 4;
            const int bb = m >> 11;
            const int s  = m & (S_ - 1);
            const size_t rowb = (size_t)(bb * H_ + h) * DH_;
            #pragma unroll
            for (int ni = 0; ni < 4; ++ni) {
                const int d = ni * 16 + lm;
                ushort4 w;
                w.x = f2bf(acc[mi][ni][0] + bia[ni]);
                w.y = f2bf(acc[mi][ni][1] + bia[ni]);
                w.z = f2bf(acc[mi][ni][2] + bia[ni]);
                w.w = f2bf(acc[mi][ni][3] + bia[ni]);
                *reinterpret_cast<ushort4*>(&Out[(rowb + d) * S_ + s]) = w;
            }
        }
    } else {
        const float qscale = (sec == 0) ? QSCALE2_ : 1.0f;
        const float nlf = -13.287712379549449f / 32.0f;   // -log2(1e4)/32
        const float invf0 = exp2f((float)lm * nlf);
        const float invf1 = exp2f((float)(lm + 16) * nlf);
        #pragma unroll
        for (int mi = 0; mi < 4; ++mi) {
            #pragma unroll
            for (int r = 0; r < 4; ++r) {
                const int m  = m0 + wm + mi * 16 + quad * 4 + r;
                const int bb = m >> 11;
                const int s  = m & (S_ - 1);
                const size_t obase = ((size_t)(bb * H_ + h) * S_ + s) * DH_;
                const float a0 = (float)s * invf0, a1 = (float)s * invf1;
                const float sn0 = __sinf(a0), cs0 = __cosf(a0);
                const float sn1 = __sinf(a1), cs1 = __cosf(a1);
                #pragma unroll
                for (int ni = 0; ni < 4; ++ni) {
                    const int d = ni * 16 + lm;
                    const float v = acc[mi][ni][r]     + bia[ni];
                    const float p = acc[mi][ni ^ 2][r] + bia[ni ^ 2];  // d^32 partner
                    const float cs = (ni & 1) ? cs1 : cs0;
                    const float sn = (ni & 1) ? sn1 : sn0;
                    float res = (d < 32) ? (v * cs - p * sn) : (v * cs + p * sn);
                    Out[obase + d] = f2bf(res * qscale);
                }
            }
        }
    }
}

// ---------------------------------------------------------------------------
// Output projection: C(64x128) tiles = A(4096x1024 bf16) * BT(1024x1024)^T.
// BM=64 -> grid 8x64 = 512 blocks = 2 blocks/CU (cross-block barrier overlap).
// ---------------------------------------------------------------------------
__global__ __launch_bounds__(256) void gemm_out(
    const unsigned short* __restrict__ A, const unsigned short* __restrict__ BT,
    const float* __restrict__ bias, float* __restrict__ Of)
{
    __shared__ unsigned short As[64 * 32];
    __shared__ unsigned short Bs[128 * 32];

    const int tid  = threadIdx.x;
    const int wave = tid >> 6;
    const int lane = tid & 63;
    const int quad = lane >> 4;
    const int lm   = lane & 15;
    const int wm = (wave >> 1) * 32;
    const int wn = (wave & 1) * 64;
    const int n0 = blockIdx.x * 128;
    const int m0 = blockIdx.y * 64;

    floatx4 acc[2][4] = {};

    const int sr = lane >> 2;
    const int sc = lane & 3;

    for (int k0 = 0; k0 < 1024; k0 += 32) {
        load_lds16(A + (size_t)(m0 + wave * 16 + sr) * 1024 + k0 + sc * 8,
                   &As[wave * 16 * 32]);
        #pragma unroll
        for (int rep = 0; rep < 2; ++rep) {
            const int r = wave * 32 + rep * 16;
            load_lds16(BT + (size_t)(n0 + r + sr) * 1024 + k0 + sc * 8, &Bs[r * 32]);
        }
        __syncthreads();
        short8 af[2], bf[4];
        #pragma unroll
        for (int i = 0; i < 2; ++i)
            af[i] = *reinterpret_cast<const short8*>(&As[(wm + i * 16 + lm) * 32 + quad * 8]);
        #pragma unroll
        for (int i = 0; i < 4; ++i)
            bf[i] = *reinterpret_cast<const short8*>(&Bs[(wn + i * 16 + lm) * 32 + quad * 8]);
        #pragma unroll
        for (int mi = 0; mi < 2; ++mi)
            #pragma unroll
            for (int ni = 0; ni < 4; ++ni)
                acc[mi][ni] = __builtin_amdgcn_mfma_f32_16x16x32_bf16(
                    af[mi], bf[ni], acc[mi][ni], 0, 0, 0);
        __syncthreads();
    }

    #pragma unroll
    for (int ni = 0; ni < 4; ++ni) {
        const int gn = n0 + wn + ni * 16 + lm;
        const float b = bias[gn];
        #pragma unroll
        for (int mi = 0; mi < 2; ++mi) {
            const int gm = m0 + wm + mi * 16 + quad * 4;
            #pragma unroll
            for (int r = 0; r < 4; ++r)
                Of[(size_t)(gm + r) * 1024 + gn] = acc[mi][ni][r] + b;
        }
    }
}

// ---------------------------------------------------------------------------
// MFMA flash attention v8: NO K/V LDS staging, NO barriers.
//  - Each wave reads its K / V^T MFMA fragments DIRECTLY from global
//    (16 rows x 64B segments per load -> coalesced; per-head K/V is
//    XCD-local in L2 since all 16 blocks of a head share bi%8).
//  - K fragments register-prefetched one iter ahead (issued after last QK
//    use); V fragments likewise (issued after last PV use) -> ~600 cyc
//    cover for ~200-400 cyc L2 latency.
//  - Waves fully independent -> s_setprio has independent waves to
//    arbitrate (m191 regime). Only per-wave P LDS remains (8.7 KB).
//  - paired causal q-tiles (31-p, p): 512 equal blocks.
// ---------------------------------------------------------------------------
static constexpr int PST = 68;   // Ps row stride

__global__ __launch_bounds__(256, 2) void flash_mfma(
    const unsigned short* __restrict__ Q, const unsigned short* __restrict__ K,
    const unsigned short* __restrict__ VT, unsigned short* __restrict__ Ao)
{
    __shared__ unsigned short Ps[4][16 * PST];     // per-wave P [q][key]

    const int bi = blockIdx.x;       // 0..511
    const int bh = bi & 31;
    const int pr = bi >> 5;          // pair index 0..15 -> tiles (31-pr, pr)
    const int h  = bh & 15;
    const int b  = bh >> 4;
    const int tid  = threadIdx.x;
    const int wave = tid >> 6;
    const int lane = tid & 63;
    const int quad = lane >> 4;
    const int lm   = lane & 15;

    const unsigned short* Kg  = K  + (size_t)bh * S_ * DH_;
    const unsigned short* VTg = VT + (size_t)bh * DH_ * S_;

    // per-lane fragment base pointers (kt = 0)
    // K frag: row (key) = t*16+lm, d chunk = quad*8 (+32); advance 64*DH_ per kt
    // V^T frag: row (d) = t*16+lm, key chunk = quad*8 (+32); advance 64 per kt
    const unsigned short* kp[4];
    const unsigned short* vp[4];
    #pragma unroll
    for (int t = 0; t < 4; ++t) {
        kp[t] = Kg  + (size_t)(t * 16 + lm) * DH_ + quad * 8;
        vp[t] = VTg + (size_t)(t * 16 + lm) * S_  + quad * 8;
    }

    // slope * MAX_BIAS * log2e
    const float slope2 = exp2f(-0.5f * (float)(h + 1)) * (8.0f * 1.44269504f);
    const float d64 = 64.0f * slope2;

    // per-t key offset relative to q: koff[t] = (t*16+quad*4) - (wave*16+lm)
    int   koff[4];
    float alb[4];
    #pragma unroll
    for (int t = 0; t < 4; ++t) {
        koff[t] = t * 16 + quad * 4 - wave * 16 - lm;
        alb[t]  = (float)koff[t] * slope2 - C8L2_;
    }

    unsigned short* Pw = &Ps[wave][0];

    for (int ph = 0; ph < 2; ++ph) {
        const int qt = ph ? pr : 31 - pr;

        // Q B-frags: col q = lm of this wave's 16-q strip
        const unsigned short* Qrow =
            Q + ((size_t)bh * S_ + (size_t)(qt * 64 + wave * 16 + lm)) * DH_;
        const short8 aq0 = *reinterpret_cast<const short8*>(Qrow + quad * 8);
        const short8 aq1 = *reinterpret_cast<const short8*>(Qrow + 32 + quad * 8);

        float crk[4];
        #pragma unroll
        for (int r = 0; r < 4; ++r)
            crk[r] = (float)r * slope2 - (float)qt * d64;

        float l_one = 0.0f;
        floatx4 acc_o[4] = {};

        // ---- prologue: load kt=0 K and V fragments ----
        short8 kf0[4], kf1[4], vf0[4], vf1[4];
        #pragma unroll
        for (int t = 0; t < 4; ++t) {
            kf0[t] = *reinterpret_cast<const short8*>(kp[t]);
            kf1[t] = *reinterpret_cast<const short8*>(kp[t] + 32);
            vf0[t] = *reinterpret_cast<const short8*>(vp[t]);
            vf1[t] = *reinterpret_cast<const short8*>(vp[t] + 32);
        }

        for (int kt = 0; kt <= qt; ++kt) {
            // ---- S^T = K Q^T (swapped operands; K frags in registers) ----
            floatx4 sacc[4] = {};
            __builtin_amdgcn_s_setprio(1);
            #pragma unroll
            for (int t = 0; t < 4; ++t) {
                sacc[t] = __builtin_amdgcn_mfma_f32_16x16x32_bf16(kf0[t], aq0, sacc[t], 0, 0, 0);
                sacc[t] = __builtin_amdgcn_mfma_f32_16x16x32_bf16(kf1[t], aq1, sacc[t], 0, 0, 0);
            }
            __builtin_amdgcn_s_setprio(0);

            // ---- prefetch next K fragments (consumed top of next iter) ----
            if (kt < qt) {
                const size_t off = (size_t)(kt + 1) * 64 * DH_;
                #pragma unroll
                for (int t = 0; t < 4; ++t) {
                    kf0[t] = *reinterpret_cast<const short8*>(kp[t] + off);
                    kf1[t] = *reinterpret_cast<const short8*>(kp[t] + off + 32);
                }
            }

            // ---- softmax: p = exp2(s + alibi); packed bf16 store ----
            const bool diag = (kt == qt);
            #pragma unroll
            for (int t = 0; t < 4; ++t) {
                float p[4];
                #pragma unroll
                for (int r = 0; r < 4; ++r) {
                    const float x = (sacc[t][r] + alb[t]) + crk[r];
                    float e;
                    asm("v_exp_f32 %0, %1" : "=v"(e) : "v"(x));
                    if (diag && (koff[t] + r) > 0) e = 0.0f;
                    p[r] = e;
                }
                l_one += (p[0] + p[1]) + (p[2] + p[3]);
                unsigned int lo, hi;
                asm("v_cvt_pk_bf16_f32 %0, %1, %2" : "=v"(lo) : "v"(p[0]), "v"(p[1]));
                asm("v_cvt_pk_bf16_f32 %0, %1, %2" : "=v"(hi) : "v"(p[2]), "v"(p[3]));
                uint2 w; w.x = lo; w.y = hi;
                *reinterpret_cast<uint2*>(&Pw[lm * PST + t * 16 + quad * 4]) = w;
            }
            #pragma unroll
            for (int r = 0; r < 4; ++r) crk[r] += d64;

            // ---- O += P V  (A=P from Ps[q][k], B=V^T frags in registers) ----
            const short8 ap0 = *reinterpret_cast<const short8*>(&Pw[lm * PST + quad * 8]);
            const short8 ap1 = *reinterpret_cast<const short8*>(&Pw[lm * PST + 32 + quad * 8]);
            __builtin_amdgcn_s_setprio(1);
            #pragma unroll
            for (int t = 0; t < 4; ++t) {
                acc_o[t] = __builtin_amdgcn_mfma_f32_16x16x32_bf16(ap0, vf0[t], acc_o[t], 0, 0, 0);
                acc_o[t] = __builtin_amdgcn_mfma_f32_16x16x32_bf16(ap1, vf1[t], acc_o[t], 0, 0, 0);
            }
            __builtin_amdgcn_s_setprio(0);

            // ---- prefetch next V fragments (consumed at next iter's PV) ----
            if (kt < qt) {
                const size_t off = (size_t)(kt + 1) * 64;
                #pragma unroll
                for (int t = 0; t < 4; ++t) {
                    vf0[t] = *reinterpret_cast<const short8*>(vp[t] + off);
                    vf1[t] = *reinterpret_cast<const short8*>(vp[t] + off + 32);
                }
            }
        }

        // ---- epilogue: l over k lives across quads -> xor 16,32; O /= l ----
        l_one += __shfl_xor(l_one, 16);
        l_one += __shfl_xor(l_one, 32);
        #pragma unroll
        for (int r = 0; r < 4; ++r) {
            const float lr = __shfl(l_one, quad * 4 + r);   // l for q-row quad*4+r
            const float inv_l = 1.0f / lr;
            const int s = qt * 64 + wave * 16 + quad * 4 + r;
            const size_t obase = ((size_t)(b * S_ + s) * H_ + h) * DH_;
            #pragma unroll
            for (int t = 0; t < 4; ++t)
                Ao[obase + t * 16 + lm] = f2bf(acc_o[t][r] * inv_l);
        }
    }
}

// ---------------------------------------------------------------------------
extern "C" void kernel_launch(void* const* d_in, const int* in_sizes, int n_in,
                              void* d_out, int out_size, void* d_ws, size_t ws_size,
                              hipStream_t stream)
{
    const float *x = nullptr, *w_qkv = nullptr, *b_qkv = nullptr,
                *w_out = nullptr, *b_out = nullptr;
    for (int i = 0; i < n_in; ++i) {
        switch (in_sizes[i]) {
            case 4194304: x     = (const float*)d_in[i]; break;
            case 3145728: w_qkv = (const float*)d_in[i]; break;
            case 3072:    b_qkv = (const float*)d_in[i]; break;
            case 1048576: w_out = (const float*)d_in[i]; break;
            case 1024:    b_out = (const float*)d_in[i]; break;
        }
    }
    if (!x)     x     = (const float*)d_in[0];
    if (!w_qkv) w_qkv = (const float*)d_in[1];
    if (!b_qkv) b_qkv = (const float*)d_in[2];
    if (!w_out) w_out = (const float*)d_in[3];
    if (!b_out) b_out = (const float*)d_in[4];

    float* out = (float*)d_out;                      // fp32 output
    unsigned short* ws16 = (unsigned short*)d_ws;

    // ws (ushort units): xb | wqkvT | woutT | Qb | Kb | Vb(V^T) | Aob = 48 MiB
    unsigned short* xb     = ws16;
    unsigned short* wqkvT  = ws16 + (size_t)4194304;
    unsigned short* woutT  = ws16 + (size_t)7340032;
    unsigned short* Qb     = ws16 + (size_t)8388608;
    unsigned short* Kb     = ws16 + (size_t)12582912;
    unsigned short* Vb     = ws16 + (size_t)16777216;
    unsigned short* Aob    = ws16 + (size_t)20971520;

    // merged prep: cvt_x + both weight transposes (one launch)
    prep<<<8192, 256, 0, stream>>>(x, xb, w_qkv, wqkvT, w_out, woutT);

    // QKV projection (MFMA) + bias + RoPE -> Q/K bf16 (B,H,S,DH), V^T (B,H,DH,S)
    gemm_qkv<<<dim3(24, 32), 256, 0, stream>>>(
        xb, wqkvT, b_qkv, Qb, Kb, Vb);
    // causal flash attention (MFMA v8, barrier-free) + ALiBi -> Aob bf16 (B,S,H*DH)
    flash_mfma<<<dim3(512), 256, 0, stream>>>(Qb, Kb, Vb, Aob);
    // output projection (MFMA, BM=64 / 512 blocks) + bias -> fp32 (B,S,DM)
    gemm_out<<<dim3(8, 64), 256, 0, stream>>>(Aob, woutT, b_out, out);
}

// Round 7
// 186.882 us; speedup vs baseline: 1.3561x; 1.3561x over previous
//
#include <hip/hip_runtime.h>
#include <math.h>

static constexpr int B_  = 2;
static constexpr int S_  = 2048;
static constexpr int H_  = 16;
static constexpr int DH_ = 64;
// Q pre-scale = 1/sqrt(192) * log2(e) so flash softmax uses raw v_exp_f32 (exp2)
static constexpr float QSCALE2_ = 0.104117589f;
static constexpr float C8L2_    = 11.5415603f;     // 8 * log2(e) (static-max shift)

typedef __attribute__((ext_vector_type(8))) short short8;   // 8 x bf16
typedef __attribute__((ext_vector_type(4))) float floatx4;  // MFMA acc

__device__ __forceinline__ float bf2f(unsigned short u) {
    union { unsigned int i; float f; } c; c.i = ((unsigned int)u) << 16; return c.f;
}
__device__ __forceinline__ unsigned short f2bf(float f) {
    union { float f; unsigned int i; } c; c.f = f;
    unsigned int x = c.i;
    unsigned int r = (x + 0x7fffu + ((x >> 16) & 1u)) >> 16;
    if ((x & 0x7f800000u) == 0x7f800000u) r = x >> 16;   // inf/nan passthrough
    return (unsigned short)r;
}
__device__ __forceinline__ void load_lds16(const unsigned short* g, unsigned short* l) {
    __builtin_amdgcn_global_load_lds(
        (const __attribute__((address_space(1))) unsigned int*)g,
        (__attribute__((address_space(3))) unsigned int*)l, 16, 0, 0);
}

// ---------------------------------------------------------------------------
// prep: one launch doing cvt_x (blocks 0..4095), w_qkv transpose
// (4096..7167), w_out transpose (7168..8191).
// ---------------------------------------------------------------------------
__global__ __launch_bounds__(256) void prep(
    const float* __restrict__ x,     unsigned short* __restrict__ xb,
    const float* __restrict__ w_qkv, unsigned short* __restrict__ wqkvT,
    const float* __restrict__ w_out, unsigned short* __restrict__ woutT)
{
    __shared__ float t[32][33];
    const int bid = blockIdx.x;
    if (bid < 4096) {
        const int i = bid * 256 + threadIdx.x;
        const float4 v = reinterpret_cast<const float4*>(x)[i];
        ushort4 r;
        r.x = f2bf(v.x); r.y = f2bf(v.y); r.z = f2bf(v.z); r.w = f2bf(v.w);
        reinterpret_cast<ushort4*>(xb)[i] = r;
        return;
    }
    const float* in; unsigned short* out; int NN, bx, by;
    if (bid < 7168) {
        in = w_qkv; out = wqkvT; NN = 3072;
        const int b2 = bid - 4096; bx = b2 % 96; by = b2 / 96;
    } else {
        in = w_out; out = woutT; NN = 1024;
        const int b2 = bid - 7168; bx = b2 & 31; by = b2 >> 5;
    }
    const int n0 = bx * 32;
    const int k0 = by * 32;
    const int tn = threadIdx.x & 31, tk = threadIdx.x >> 5;   // tk 0..7
    #pragma unroll
    for (int i = 0; i < 4; ++i)
        t[tk + 8 * i][tn] = in[(size_t)(k0 + tk + 8 * i) * NN + n0 + tn];
    __syncthreads();
    #pragma unroll
    for (int i = 0; i < 4; ++i)
        out[(size_t)(n0 + tk + 8 * i) * 1024 + k0 + tn] = f2bf(t[tn][tk + 8 * i]);
}

// ---------------------------------------------------------------------------
// MFMA GEMM: C(128x128) = A(Mx1024 bf16) * BT(3072x1024 bf16)^T.
// bias + RoPE epilogue:
//   Q -> bf16 (B,H,S,DH), scaled by 1/sqrt(192)*log2e
//   K -> bf16 (B,H,S,DH)
//   V -> bf16 (B,H,DH,S)  TRANSPOSED (so flash stages V^T with vector ops)
// ---------------------------------------------------------------------------
__global__ __launch_bounds__(256) void gemm_qkv(
    const unsigned short* __restrict__ A, const unsigned short* __restrict__ BT,
    const float* __restrict__ bias,
    unsigned short* __restrict__ O0, unsigned short* __restrict__ O1,
    unsigned short* __restrict__ O2)
{
    __shared__ unsigned short As[128 * 32];
    __shared__ unsigned short Bs[128 * 32];

    const int tid  = threadIdx.x;
    const int wave = tid >> 6;
    const int lane = tid & 63;
    const int quad = lane >> 4;
    const int lm   = lane & 15;
    const int wm = (wave >> 1) * 64;
    const int wn = (wave & 1) * 64;
    const int n0 = blockIdx.x * 128;
    const int m0 = blockIdx.y * 128;

    floatx4 acc[4][4] = {};

    const int sr = lane >> 2;
    const int sc = lane & 3;

    for (int k0 = 0; k0 < 1024; k0 += 32) {
        #pragma unroll
        for (int rep = 0; rep < 2; ++rep) {
            const int r = wave * 32 + rep * 16;
            load_lds16(A  + (size_t)(m0 + r + sr) * 1024 + k0 + sc * 8, &As[r * 32]);
            load_lds16(BT + (size_t)(n0 + r + sr) * 1024 + k0 + sc * 8, &Bs[r * 32]);
        }
        __syncthreads();
        short8 af[4], bf[4];
        #pragma unroll
        for (int i = 0; i < 4; ++i) {
            af[i] = *reinterpret_cast<const short8*>(&As[(wm + i * 16 + lm) * 32 + quad * 8]);
            bf[i] = *reinterpret_cast<const short8*>(&Bs[(wn + i * 16 + lm) * 32 + quad * 8]);
        }
        #pragma unroll
        for (int mi = 0; mi < 4; ++mi)
            #pragma unroll
            for (int ni = 0; ni < 4; ++ni)
                acc[mi][ni] = __builtin_amdgcn_mfma_f32_16x16x32_bf16(
                    af[mi], bf[ni], acc[mi][ni], 0, 0, 0);
        __syncthreads();
    }

    const int nbase = n0 + wn;
    const int h   = nbase / 192;
    const int sec = (nbase - h * 192) >> 6;      // 0=q 1=k 2=v
    float bia[4];
    #pragma unroll
    for (int ni = 0; ni < 4; ++ni) bia[ni] = bias[nbase + ni * 16 + lm];
    unsigned short* Out = (sec == 0) ? O0 : ((sec == 1) ? O1 : O2);

    if (sec == 2) {
        // V^T store: (B,H,DH,S); lane holds 4 consecutive s -> ushort4
        #pragma unroll
        for (int mi = 0; mi < 4; ++mi) {
            const int m  = m0 + wm + mi * 16 + quad * 4;
            const int bb = m >> 11;
            const int s  = m & (S_ - 1);
            const size_t rowb = (size_t)(bb * H_ + h) * DH_;
            #pragma unroll
            for (int ni = 0; ni < 4; ++ni) {
                const int d = ni * 16 + lm;
                ushort4 w;
                w.x = f2bf(acc[mi][ni][0] + bia[ni]);
                w.y = f2bf(acc[mi][ni][1] + bia[ni]);
                w.z = f2bf(acc[mi][ni][2] + bia[ni]);
                w.w = f2bf(acc[mi][ni][3] + bia[ni]);
                *reinterpret_cast<ushort4*>(&Out[(rowb + d) * S_ + s]) = w;
            }
        }
    } else {
        const float qscale = (sec == 0) ? QSCALE2_ : 1.0f;
        const float nlf = -13.287712379549449f / 32.0f;   // -log2(1e4)/32
        const float invf0 = exp2f((float)lm * nlf);
        const float invf1 = exp2f((float)(lm + 16) * nlf);
        #pragma unroll
        for (int mi = 0; mi < 4; ++mi) {
            #pragma unroll
            for (int r = 0; r < 4; ++r) {
                const int m  = m0 + wm + mi * 16 + quad * 4 + r;
                const int bb = m >> 11;
                const int s  = m & (S_ - 1);
                const size_t obase = ((size_t)(bb * H_ + h) * S_ + s) * DH_;
                const float a0 = (float)s * invf0, a1 = (float)s * invf1;
                const float sn0 = __sinf(a0), cs0 = __cosf(a0);
                const float sn1 = __sinf(a1), cs1 = __cosf(a1);
                #pragma unroll
                for (int ni = 0; ni < 4; ++ni) {
                    const int d = ni * 16 + lm;
                    const float v = acc[mi][ni][r]     + bia[ni];
                    const float p = acc[mi][ni ^ 2][r] + bia[ni ^ 2];  // d^32 partner
                    const float cs = (ni & 1) ? cs1 : cs0;
                    const float sn = (ni & 1) ? sn1 : sn0;
                    float res = (d < 32) ? (v * cs - p * sn) : (v * cs + p * sn);
                    Out[obase + d] = f2bf(res * qscale);
                }
            }
        }
    }
}

// ---------------------------------------------------------------------------
// Output projection: C(64x128) tiles = A(4096x1024 bf16) * BT(1024x1024)^T.
// BM=64 -> grid 8x64 = 512 blocks = 2 blocks/CU (cross-block barrier overlap).
// ---------------------------------------------------------------------------
__global__ __launch_bounds__(256) void gemm_out(
    const unsigned short* __restrict__ A, const unsigned short* __restrict__ BT,
    const float* __restrict__ bias, float* __restrict__ Of)
{
    __shared__ unsigned short As[64 * 32];
    __shared__ unsigned short Bs[128 * 32];

    const int tid  = threadIdx.x;
    const int wave = tid >> 6;
    const int lane = tid & 63;
    const int quad = lane >> 4;
    const int lm   = lane & 15;
    const int wm = (wave >> 1) * 32;
    const int wn = (wave & 1) * 64;
    const int n0 = blockIdx.x * 128;
    const int m0 = blockIdx.y * 64;

    floatx4 acc[2][4] = {};

    const int sr = lane >> 2;
    const int sc = lane & 3;

    for (int k0 = 0; k0 < 1024; k0 += 32) {
        load_lds16(A + (size_t)(m0 + wave * 16 + sr) * 1024 + k0 + sc * 8,
                   &As[wave * 16 * 32]);
        #pragma unroll
        for (int rep = 0; rep < 2; ++rep) {
            const int r = wave * 32 + rep * 16;
            load_lds16(BT + (size_t)(n0 + r + sr) * 1024 + k0 + sc * 8, &Bs[r * 32]);
        }
        __syncthreads();
        short8 af[2], bf[4];
        #pragma unroll
        for (int i = 0; i < 2; ++i)
            af[i] = *reinterpret_cast<const short8*>(&As[(wm + i * 16 + lm) * 32 + quad * 8]);
        #pragma unroll
        for (int i = 0; i < 4; ++i)
            bf[i] = *reinterpret_cast<const short8*>(&Bs[(wn + i * 16 + lm) * 32 + quad * 8]);
        #pragma unroll
        for (int mi = 0; mi < 2; ++mi)
            #pragma unroll
            for (int ni = 0; ni < 4; ++ni)
                acc[mi][ni] = __builtin_amdgcn_mfma_f32_16x16x32_bf16(
                    af[mi], bf[ni], acc[mi][ni], 0, 0, 0);
        __syncthreads();
    }

    #pragma unroll
    for (int ni = 0; ni < 4; ++ni) {
        const int gn = n0 + wn + ni * 16 + lm;
        const float b = bias[gn];
        #pragma unroll
        for (int mi = 0; mi < 2; ++mi) {
            const int gm = m0 + wm + mi * 16 + quad * 4;
            #pragma unroll
            for (int r = 0; r < 4; ++r)
                Of[(size_t)(gm + r) * 1024 + gn] = acc[mi][ni][r] + b;
        }
    }
}

// ---------------------------------------------------------------------------
// MFMA flash attention v9: 8-wave blocks, hi/lo tile pair CONCURRENT.
//  - waves 0-3: q-tile 31-p; waves 4-7: q-tile p. One shared double-buffered
//    K/V^T staging (lo's kt range is a subset of hi's) -> per-thread staging
//    halves, resident waves double (4/SIMD), block-iters = 32-p (was 33).
//  - swapped QK^T (P-store = cvt_pk + b64), exp2-space softmax, dbuf
//    1-barrier loop, register prefetch 2 tiles ahead (all from v7).
// ---------------------------------------------------------------------------
static constexpr int KST = 68;   // Ks/VTs row stride (ushorts)
static constexpr int PST = 68;   // Ps row stride

__global__ __launch_bounds__(512, 4) void flash_mfma(
    const unsigned short* __restrict__ Q, const unsigned short* __restrict__ K,
    const unsigned short* __restrict__ VT, unsigned short* __restrict__ Ao)
{
    __shared__ unsigned short Ks[2][64 * KST];     // [buf][key][d] padded
    __shared__ unsigned short VTs[2][64 * KST];    // [buf][d][key] padded
    __shared__ unsigned short Ps[8][16 * PST];     // per-wave P [q][key]

    const int bi = blockIdx.x;       // 0..511
    const int bh = bi & 31;
    const int p  = bi >> 5;          // 0..15
    const int h  = bh & 15;
    const int b  = bh >> 4;
    const int tid  = threadIdx.x;    // 0..511
    const int wave = tid >> 6;       // 0..7
    const int lane = tid & 63;
    const int quad = lane >> 4;
    const int lm   = lane & 15;
    const int wq   = wave & 3;       // strip within the tile
    const int qt   = (wave < 4) ? (31 - p) : p;   // per-wave q-tile
    const int nkt  = 32 - p;         // block iterations: kt = 0 .. 31-p
    const int srow = tid >> 3;       // staging row 0..63
    const int sc8  = tid & 7;        // staging chunk 0..7 (8 ushorts each)

    const unsigned short* Kg  = K  + (size_t)bh * S_ * DH_;
    const unsigned short* VTg = VT + (size_t)bh * DH_ * S_;

    // slope * MAX_BIAS * log2e
    const float slope2 = exp2f(-0.5f * (float)(h + 1)) * (8.0f * 1.44269504f);
    const float d64 = 64.0f * slope2;

    // per-t key offset relative to q: koff[t] = (t*16+quad*4) - (wq*16+lm)
    int   koff[4];
    float alb[4];
    #pragma unroll
    for (int t = 0; t < 4; ++t) {
        koff[t] = t * 16 + quad * 4 - wq * 16 - lm;
        alb[t]  = (float)koff[t] * slope2 - C8L2_;
    }

    unsigned short* Pw = &Ps[wave][0];

    // Q B-frags: col q = lm of this wave's 16-q strip
    const unsigned short* Qrow =
        Q + ((size_t)bh * S_ + (size_t)(qt * 64 + wq * 16 + lm)) * DH_;
    const short8 aq0 = *reinterpret_cast<const short8*>(Qrow + quad * 8);
    const short8 aq1 = *reinterpret_cast<const short8*>(Qrow + 32 + quad * 8);

    float crk[4];
    #pragma unroll
    for (int r = 0; r < 4; ++r)
        crk[r] = (float)r * slope2 - (float)qt * d64;

    float l_one = 0.0f;
    floatx4 acc_o[4] = {};

    // ---- prologue: T0 -> regs -> buf0; T1 -> regs (nkt >= 17 always) ----
    short8 ka, va;
    ka = *reinterpret_cast<const short8*>(Kg + (size_t)srow * DH_ + sc8 * 8);
    va = *reinterpret_cast<const short8*>(VTg + (size_t)srow * S_ + sc8 * 8);
    *reinterpret_cast<short8*>(&Ks[0][srow * KST + sc8 * 8])  = ka;
    *reinterpret_cast<short8*>(&VTs[0][srow * KST + sc8 * 8]) = va;
    ka = *reinterpret_cast<const short8*>(Kg + (size_t)(64 + srow) * DH_ + sc8 * 8);
    va = *reinterpret_cast<const short8*>(VTg + (size_t)srow * S_ + 64 + sc8 * 8);
    __syncthreads();

    for (int kt = 0; kt < nkt; ++kt) {
        const int cur = kt & 1;

        // ---- write tile kt+1 (in regs) to buf^1; issue loads for kt+2 ----
        if (kt + 1 < nkt) {
            const int nxt = cur ^ 1;
            *reinterpret_cast<short8*>(&Ks[nxt][srow * KST + sc8 * 8])  = ka;
            *reinterpret_cast<short8*>(&VTs[nxt][srow * KST + sc8 * 8]) = va;
            if (kt + 2 < nkt) {
                ka = *reinterpret_cast<const short8*>(
                    Kg + (size_t)((kt + 2) * 64 + srow) * DH_ + sc8 * 8);
                va = *reinterpret_cast<const short8*>(
                    VTg + (size_t)srow * S_ + (kt + 2) * 64 + sc8 * 8);
            }
        }

        if (kt <= qt) {   // lo-tile waves stop computing after kt = p
            // ---- S^T = K Q^T (swapped operands) ----
            floatx4 sacc[4] = {};
            __builtin_amdgcn_s_setprio(1);
            #pragma unroll
            for (int t = 0; t < 4; ++t) {
                const short8 k0 = *reinterpret_cast<const short8*>(&Ks[cur][(t * 16 + lm) * KST + quad * 8]);
                const short8 k1 = *reinterpret_cast<const short8*>(&Ks[cur][(t * 16 + lm) * KST + 32 + quad * 8]);
                sacc[t] = __builtin_amdgcn_mfma_f32_16x16x32_bf16(k0, aq0, sacc[t], 0, 0, 0);
                sacc[t] = __builtin_amdgcn_mfma_f32_16x16x32_bf16(k1, aq1, sacc[t], 0, 0, 0);
            }
            __builtin_amdgcn_s_setprio(0);

            // ---- softmax: p = exp2(s + alibi); packed bf16 store ----
            const bool diag = (kt == qt);
            #pragma unroll
            for (int t = 0; t < 4; ++t) {
                float pv[4];
                #pragma unroll
                for (int r = 0; r < 4; ++r) {
                    const float x = (sacc[t][r] + alb[t]) + crk[r];
                    float e;
                    asm("v_exp_f32 %0, %1" : "=v"(e) : "v"(x));
                    if (diag && (koff[t] + r) > 0) e = 0.0f;
                    pv[r] = e;
                }
                l_one += (pv[0] + pv[1]) + (pv[2] + pv[3]);
                unsigned int lo, hi;
                asm("v_cvt_pk_bf16_f32 %0, %1, %2" : "=v"(lo) : "v"(pv[0]), "v"(pv[1]));
                asm("v_cvt_pk_bf16_f32 %0, %1, %2" : "=v"(hi) : "v"(pv[2]), "v"(pv[3]));
                uint2 w; w.x = lo; w.y = hi;
                *reinterpret_cast<uint2*>(&Pw[lm * PST + t * 16 + quad * 4]) = w;
            }
            #pragma unroll
            for (int r = 0; r < 4; ++r) crk[r] += d64;

            // ---- O += P V  (A=P from Ps[q][k], B=V^T) ----
            const short8 ap0 = *reinterpret_cast<const short8*>(&Pw[lm * PST + quad * 8]);
            const short8 ap1 = *reinterpret_cast<const short8*>(&Pw[lm * PST + 32 + quad * 8]);
            __builtin_amdgcn_s_setprio(1);
            #pragma unroll
            for (int t = 0; t < 4; ++t) {
                const short8 v0 = *reinterpret_cast<const short8*>(&VTs[cur][(t * 16 + lm) * KST + quad * 8]);
                const short8 v1 = *reinterpret_cast<const short8*>(&VTs[cur][(t * 16 + lm) * KST + 32 + quad * 8]);
                acc_o[t] = __builtin_amdgcn_mfma_f32_16x16x32_bf16(ap0, v0, acc_o[t], 0, 0, 0);
                acc_o[t] = __builtin_amdgcn_mfma_f32_16x16x32_bf16(ap1, v1, acc_o[t], 0, 0, 0);
            }
            __builtin_amdgcn_s_setprio(0);
        }
        __syncthreads();   // separates reads of buf[cur] from next iter's writes
    }

    // ---- epilogue: l over k lives across quads -> xor 16,32; O /= l ----
    l_one += __shfl_xor(l_one, 16);
    l_one += __shfl_xor(l_one, 32);
    #pragma unroll
    for (int r = 0; r < 4; ++r) {
        const float lr = __shfl(l_one, quad * 4 + r);   // l for q-row quad*4+r
        const float inv_l = 1.0f / lr;
        const int s = qt * 64 + wq * 16 + quad * 4 + r;
        const size_t obase = ((size_t)(b * S_ + s) * H_ + h) * DH_;
        #pragma unroll
        for (int t = 0; t < 4; ++t)
            Ao[obase + t * 16 + lm] = f2bf(acc_o[t][r] * inv_l);
    }
}

// ---------------------------------------------------------------------------
extern "C" void kernel_launch(void* const* d_in, const int* in_sizes, int n_in,
                              void* d_out, int out_size, void* d_ws, size_t ws_size,
                              hipStream_t stream)
{
    const float *x = nullptr, *w_qkv = nullptr, *b_qkv = nullptr,
                *w_out = nullptr, *b_out = nullptr;
    for (int i = 0; i < n_in; ++i) {
        switch (in_sizes[i]) {
            case 4194304: x     = (const float*)d_in[i]; break;
            case 3145728: w_qkv = (const float*)d_in[i]; break;
            case 3072:    b_qkv = (const float*)d_in[i]; break;
            case 1048576: w_out = (const float*)d_in[i]; break;
            case 1024:    b_out = (const float*)d_in[i]; break;
        }
    }
    if (!x)     x     = (const float*)d_in[0];
    if (!w_qkv) w_qkv = (const float*)d_in[1];
    if (!b_qkv) b_qkv = (const float*)d_in[2];
    if (!w_out) w_out = (const float*)d_in[3];
    if (!b_out) b_out = (const float*)d_in[4];

    float* out = (float*)d_out;                      // fp32 output
    unsigned short* ws16 = (unsigned short*)d_ws;

    // ws (ushort units): xb | wqkvT | woutT | Qb | Kb | Vb(V^T) | Aob = 48 MiB
    unsigned short* xb     = ws16;
    unsigned short* wqkvT  = ws16 + (size_t)4194304;
    unsigned short* woutT  = ws16 + (size_t)7340032;
    unsigned short* Qb     = ws16 + (size_t)8388608;
    unsigned short* Kb     = ws16 + (size_t)12582912;
    unsigned short* Vb     = ws16 + (size_t)16777216;
    unsigned short* Aob    = ws16 + (size_t)20971520;

    // merged prep: cvt_x + both weight transposes (one launch)
    prep<<<8192, 256, 0, stream>>>(x, xb, w_qkv, wqkvT, w_out, woutT);

    // QKV projection (MFMA) + bias + RoPE -> Q/K bf16 (B,H,S,DH), V^T (B,H,DH,S)
    gemm_qkv<<<dim3(24, 32), 256, 0, stream>>>(
        xb, wqkvT, b_qkv, Qb, Kb, Vb);
    // causal flash attention (MFMA v9, 8-wave hi/lo pair) + ALiBi -> Aob bf16
    flash_mfma<<<dim3(512), 512, 0, stream>>>(Qb, Kb, Vb, Aob);
    // output projection (MFMA, BM=64 / 512 blocks) + bias -> fp32 (B,S,DM)
    gemm_out<<<dim3(8, 64), 256, 0, stream>>>(Aob, woutT, b_out, out);
}